// Round 9
// baseline (131.438 us; speedup 1.0000x reference)
//
#include <hip/hip_runtime.h>
#include <math.h>

#define NSAMP 32
#define XSTR  36                  // LDS row stride in floats (144B rows, 16B-aligned)
#define SQRT3 1.7320508075688772f

typedef _Float16 half8  __attribute__((ext_vector_type(8)));
typedef float    f32x16 __attribute__((ext_vector_type(16)));

// whole-wave broadcast from lane L (compile-time) — VALU op, ~4cy dependent latency
__device__ __forceinline__ float rdlane(float v, int l) {
    return __int_as_float(__builtin_amdgcn_readlane(__float_as_int(v), l));
}

// dual interleaved register Cholesky: two independent chains fill each other's stalls
template<int K, int JJ>
struct Upd2 {
    static __device__ __forceinline__ void run(float* a, float* b, float la, float lb) {
        a[JJ] = fmaf(-la, rdlane(la, JJ), a[JJ]);
        b[JJ] = fmaf(-lb, rdlane(lb, JJ), b[JJ]);
        Upd2<K, JJ + 1>::run(a, b, la, lb);
    }
};
template<int K>
struct Upd2<K, NSAMP> { static __device__ __forceinline__ void run(float*, float*, float, float) {} };

template<int K>
struct Chol2 {
    static __device__ __forceinline__ void run(float* a, float* b) {
        float la = a[K] * __frsqrt_rn(rdlane(a[K], K));
        float lb = b[K] * __frsqrt_rn(rdlane(b[K], K));
        a[K] = la; b[K] = lb;
        Upd2<K, K + 1>::run(a, b, la, lb);
        Chol2<K + 1>::run(a, b);
    }
};
template<>
struct Chol2<NSAMP> { static __device__ __forceinline__ void run(float*, float*) {} };

__global__ __launch_bounds__(256, 4) void tmk_kernel(
    const float* __restrict__ aug,     // (32, n_loc, 31)
    const float* __restrict__ scales,  // (n_loc)
    const float* __restrict__ nug,     // (n_loc)
    const float* __restrict__ frac,    // (1)
    const int*   __restrict__ bidx,    // (n_loc)
    const float* __restrict__ thq,     // (1)
    const float* __restrict__ sigp,    // (2)
    const float* __restrict__ lens,    // (1)
    float* __restrict__ out,
    int n_loc)
{
    // all LDS is wave-private -> no __syncthreads anywhere
    __shared__ __align__(16) float X[4][NSAMP][XSTR];
    __shared__ float SQ[4][NSAMP];

    const int tid  = threadIdx.x;
    const int w    = tid >> 6;        // wave index within block
    const int lane = tid & 63;
    const int j    = lane & 31;       // Gram row/col owned by this lane
    const int hl   = lane >> 5;       // lane half: k-slice for MFMA, location for store
    const int kb   = 8 * hl;

    const int locA = blockIdx.x * 8 + w * 2;            // 30000 % 8 == 0: clamp never fires
    int locB = locA + 1; if (locB >= n_loc) locB = n_loc - 1;

    const size_t srow = (size_t)n_loc * 31;

    // ---- uniform scalars + per-lane feature scales ----
    const float a_s   = -0.5f * __expf(thq[0]);
    const float invls = 1.0f / (__expf(lens[0]) * SQRT3);
    float sl[8], sh[8];
#pragma unroll
    for (int e = 0; e < 8; ++e) {
        sl[e] = __expf(a_s * (float)(kb + e + 1))  * invls;   // k = kb+e
        sh[e] = __expf(a_s * (float)(kb + e + 17)) * invls;   // k = 16+kb+e
    }
    const float fr = frac[0], sp0 = sigp[0], sp1 = sigp[1];

    // zero-pad k=30,31 for all 32 rows (staging never touches these)
    X[w][lane >> 1][30 + (lane & 1)] = 0.0f;

    float av[32];                      // row j of G_A (all lanes)
    float bv[32];                      // row j of G_B (all lanes)

    // ================= PHASE A: location locA =================
    if (lane < 60) {
        const int s0 = lane / 30;
        const int k  = lane - s0 * 30;
        const float* p = aug + (size_t)s0 * srow + (size_t)locA * 31 + 1 + k;
        float* xp = &X[w][s0][k];
#pragma unroll
        for (int it = 0; it < 16; ++it) {
            float v = p[(size_t)(2 * it) * srow];
            v = (v != v) ? 0.0f : v;
            xp[2 * it * XSTR] = v;
        }
    }
    {
        const float* xr = &X[w][j][0];
        float4 r0 = *reinterpret_cast<const float4*>(xr + kb);
        float4 r1 = *reinterpret_cast<const float4*>(xr + kb + 4);
        float4 r2 = *reinterpret_cast<const float4*>(xr + 16 + kb);
        float4 r3 = *reinterpret_cast<const float4*>(xr + 16 + kb + 4);
        float v0[8] = {r0.x, r0.y, r0.z, r0.w, r1.x, r1.y, r1.z, r1.w};
        float v1[8] = {r2.x, r2.y, r2.z, r2.w, r3.x, r3.y, r3.z, r3.w};

        half8 fLoA, fHiA;
        float s0a = 0.f, s1a = 0.f;
#pragma unroll
        for (int e = 0; e < 8; ++e) {
            float a = v0[e] * sl[e];
            s0a = fmaf(a, a, s0a);
            fLoA[e] = (_Float16)a;
            float b = v1[e] * sh[e];
            s1a = fmaf(b, b, s1a);
            fHiA[e] = (_Float16)b;
        }
        float sqp     = s0a + s1a;
        float sqfullA = sqp + __shfl_xor(sqp, 32);
        if (hl == 0) SQ[w][j] = sqfullA;

        f32x16 C1 = {};
        C1 = __builtin_amdgcn_mfma_f32_32x32x16_f16(fLoA, fLoA, C1, 0, 0, 0);
        C1 = __builtin_amdgcn_mfma_f32_32x32x16_f16(fHiA, fHiA, C1, 0, 0, 0);

        const float sclA = scales[locA];
        const float sigA = __expf(sp0 + sp1 * __logf(sclA));
        const float coefA = fr * sigA * sigA / nug[locA];
        const bool  bzA   = (bidx[locA] == 0);

        float* goutA = out + (size_t)locA * 1024;
        const float* sqb = &SQ[w][4 * hl];
#pragma unroll
        for (int r = 0; r < 16; ++r) {
            const int row0 = (r & 3) + 8 * (r >> 2);
            const int i    = row0 + 4 * hl;
            const bool dia = (j == i);
            float sqi = sqb[row0];
            float d2  = fmaf(-2.0f, C1[r], sqi + sqfullA);
            d2 = dia ? 0.0f : fmaxf(d2, 0.0f);
            float s3d = __fsqrt_rn(3.0f * d2);
            float nl  = (1.0f + s3d) * __expf(-s3d);
            float dg  = dia ? 1.0f : 0.0f;
            float gv  = fmaf(coefA, nl, dg);
            if (bzA) gv = dg;
            goutA[i * 32 + j] = gv;

            float pg = __shfl_xor(gv, 32);
            av[row0]     = hl ? pg : gv;     // ALL lanes: full row j of G_A
            av[row0 + 4] = hl ? gv : pg;
        }
    }

    // keep Phase-A DS reads ordered before Phase-B DS writes;
    // allow VMEM_READ (Phase-B staging loads) to hoist across for latency hiding
    __builtin_amdgcn_sched_barrier(0x20);

    // ================= PHASE B: location locB =================
    if (lane < 60) {
        const int s0 = lane / 30;
        const int k  = lane - s0 * 30;
        const float* p = aug + (size_t)s0 * srow + (size_t)locB * 31 + 1 + k;
        float* xp = &X[w][s0][k];
#pragma unroll
        for (int it = 0; it < 16; ++it) {
            float v = p[(size_t)(2 * it) * srow];
            v = (v != v) ? 0.0f : v;
            xp[2 * it * XSTR] = v;
        }
    }
    {
        const float* xr = &X[w][j][0];
        float4 r0 = *reinterpret_cast<const float4*>(xr + kb);
        float4 r1 = *reinterpret_cast<const float4*>(xr + kb + 4);
        float4 r2 = *reinterpret_cast<const float4*>(xr + 16 + kb);
        float4 r3 = *reinterpret_cast<const float4*>(xr + 16 + kb + 4);
        float v0[8] = {r0.x, r0.y, r0.z, r0.w, r1.x, r1.y, r1.z, r1.w};
        float v1[8] = {r2.x, r2.y, r2.z, r2.w, r3.x, r3.y, r3.z, r3.w};

        half8 fLoB, fHiB;
        float s0a = 0.f, s1a = 0.f;
#pragma unroll
        for (int e = 0; e < 8; ++e) {
            float a = v0[e] * sl[e];
            s0a = fmaf(a, a, s0a);
            fLoB[e] = (_Float16)a;
            float b = v1[e] * sh[e];
            s1a = fmaf(b, b, s1a);
            fHiB[e] = (_Float16)b;
        }
        float sqp     = s0a + s1a;
        float sqfullB = sqp + __shfl_xor(sqp, 32);
        if (hl == 0) SQ[w][j] = sqfullB;

        f32x16 C2 = {};
        C2 = __builtin_amdgcn_mfma_f32_32x32x16_f16(fLoB, fLoB, C2, 0, 0, 0);
        C2 = __builtin_amdgcn_mfma_f32_32x32x16_f16(fHiB, fHiB, C2, 0, 0, 0);

        const float sclB = scales[locB];
        const float sigB = __expf(sp0 + sp1 * __logf(sclB));
        const float coefB = fr * sigB * sigB / nug[locB];
        const bool  bzB   = (bidx[locB] == 0);

        float* goutB = out + (size_t)locB * 1024;
        const float* sqb = &SQ[w][4 * hl];
#pragma unroll
        for (int r = 0; r < 16; ++r) {
            const int row0 = (r & 3) + 8 * (r >> 2);
            const int i    = row0 + 4 * hl;
            const bool dia = (j == i);
            float sqi = sqb[row0];
            float d2  = fmaf(-2.0f, C2[r], sqi + sqfullB);
            d2 = dia ? 0.0f : fmaxf(d2, 0.0f);
            float s3d = __fsqrt_rn(3.0f * d2);
            float nl  = (1.0f + s3d) * __expf(-s3d);
            float dg  = dia ? 1.0f : 0.0f;
            float gv  = fmaf(coefB, nl, dg);
            if (bzB) gv = dg;
            goutB[i * 32 + j] = gv;

            float pg = __shfl_xor(gv, 32);
            bv[row0]     = hl ? pg : gv;     // ALL lanes: full row j of G_B
            bv[row0 + 4] = hl ? gv : pg;
        }
    }

    // ---- dual interleaved Cholesky (chains hide each other's latency) ----
    Chol2<0>::run(av, bv);

    // ---- masked L row store: lanes 0-31 -> locA from av, lanes 32-63 -> locB from bv ----
    {
        const int locS = hl ? locB : locA;
        float* lrow = out + (size_t)n_loc * 1024 + (size_t)locS * 1024 + (size_t)j * 32;
#pragma unroll
        for (int c = 0; c < 8; ++c) {
            float4 wv;   // static register indices; hl-select compiles to cndmask
            wv.x = (4 * c + 0 <= j) ? (hl ? bv[4 * c + 0] : av[4 * c + 0]) : 0.f;
            wv.y = (4 * c + 1 <= j) ? (hl ? bv[4 * c + 1] : av[4 * c + 1]) : 0.f;
            wv.z = (4 * c + 2 <= j) ? (hl ? bv[4 * c + 2] : av[4 * c + 2]) : 0.f;
            wv.w = (4 * c + 3 <= j) ? (hl ? bv[4 * c + 3] : av[4 * c + 3]) : 0.f;
            *reinterpret_cast<float4*>(&lrow[4 * c]) = wv;
        }
    }

    // ---- nug_mean passthrough ----
    if (tid < 8) {
        int lc = blockIdx.x * 8 + tid; if (lc >= n_loc) lc = n_loc - 1;
        out[(size_t)n_loc * 2048 + lc] = nug[lc];
    }
}

extern "C" void kernel_launch(void* const* d_in, const int* in_sizes, int n_in,
                              void* d_out, int out_size, void* d_ws, size_t ws_size,
                              hipStream_t stream) {
    const float* aug    = (const float*)d_in[0];
    const float* scales = (const float*)d_in[1];
    const float* nug    = (const float*)d_in[2];
    const float* frac   = (const float*)d_in[3];
    const int*   bidx   = (const int*)  d_in[4];
    const float* thq    = (const float*)d_in[5];
    const float* sigp   = (const float*)d_in[6];
    const float* lens   = (const float*)d_in[7];
    const int n_loc = in_sizes[1];

    const int nblk = (n_loc + 7) / 8;
    tmk_kernel<<<nblk, 256, 0, stream>>>(aug, scales, nug, frac, bidx, thq,
                                         sigp, lens, (float*)d_out, n_loc);
}

// Round 10
// 117.776 us; speedup vs baseline: 1.1160x; 1.1160x over previous
//
#include <hip/hip_runtime.h>
#include <math.h>

#define NSAMP 32
#define XSTR  36                  // LDS row stride in floats (144B rows, 16B-aligned)
#define SQRT3 1.7320508075688772f

typedef _Float16 half8  __attribute__((ext_vector_type(8)));
typedef float    f32x16 __attribute__((ext_vector_type(16)));

// whole-wave broadcast from lane L (compile-time) — VALU op writing SGPR
__device__ __forceinline__ float rdlane(float v, int l) {
    return __int_as_float(__builtin_amdgcn_readlane(__float_as_int(v), l));
}

template<int K, int JJ>
struct Upd {
    static __device__ __forceinline__ void run(float* av, float lik) {
        av[JJ] = fmaf(-lik, rdlane(lik, JJ), av[JJ]);   // A[i][jj] -= L[i][k]*L[jj][k]
        Upd<K, JJ + 1>::run(av, lik);
    }
};
template<int K>
struct Upd<K, NSAMP> { static __device__ __forceinline__ void run(float*, float) {} };

template<int K>
struct Chol {
    static __device__ __forceinline__ void run(float* av) {
        float lik = av[K] * __frsqrt_rn(rdlane(av[K], K));  // L[i][k], i>=k
        av[K] = lik;
        Upd<K, K + 1>::run(av, lik);
        Chol<K + 1>::run(av);
    }
};
template<>
struct Chol<NSAMP> { static __device__ __forceinline__ void run(float*) {} };

// ================= K1: build g (MFMA gram + matern epilogue) =================
__global__ __launch_bounds__(256, 6) void g_kernel(
    const float* __restrict__ aug,     // (32, n_loc, 31)
    const float* __restrict__ scales,  // (n_loc)
    const float* __restrict__ nug,     // (n_loc)
    const float* __restrict__ frac,    // (1)
    const int*   __restrict__ bidx,    // (n_loc)
    const float* __restrict__ thq,     // (1)
    const float* __restrict__ sigp,    // (2)
    const float* __restrict__ lens,    // (1)
    float* __restrict__ out,
    int n_loc)
{
    // all LDS is wave-private -> no __syncthreads anywhere
    __shared__ __align__(16) float X[4][NSAMP][XSTR];
    __shared__ float SQ[4][NSAMP];

    const int tid  = threadIdx.x;
    const int w    = tid >> 6;        // wave index = which location of this block
    const int lane = tid & 63;
    const int j    = lane & 31;       // Gram column owned by this lane
    const int hl   = lane >> 5;       // k-slice half
    const int kb   = 8 * hl;

    const int loc0 = blockIdx.x * 4;
    int loc = loc0 + w; if (loc >= n_loc) loc = n_loc - 1;

    const size_t srow = (size_t)n_loc * 31;

    // ---- uniform scalars + per-lane feature scales ----
    const float a_s   = -0.5f * __expf(thq[0]);
    const float invls = 1.0f / (__expf(lens[0]) * SQRT3);
    float sl[8], sh[8];
#pragma unroll
    for (int e = 0; e < 8; ++e) {
        sl[e] = __expf(a_s * (float)(kb + e + 1))  * invls;   // k = kb+e
        sh[e] = __expf(a_s * (float)(kb + e + 17)) * invls;   // k = 16+kb+e
    }

    // ---- stage this wave's location coalesced into X[w] (NaN-fixed) ----
    if (lane < 60) {
        const int s0 = lane / 30;           // 0,1
        const int k  = lane - s0 * 30;      // 0..29
        const float* p = aug + (size_t)s0 * srow + (size_t)loc * 31 + 1 + k;
        float* xp = &X[w][s0][k];
#pragma unroll
        for (int it = 0; it < 16; ++it) {   // s = 2*it + s0 covers 0..31
            float v = p[(size_t)(2 * it) * srow];
            v = (v != v) ? 0.0f : v;        // isnan -> 0
            xp[2 * it * XSTR] = v;
        }
    }
    // zero-pad k=30,31 for all 32 rows
    X[w][lane >> 1][30 + (lane & 1)] = 0.0f;

    // ---- frag load (row j, own k-slice) + scale + f16 convert + norm ----
    const float* xr = &X[w][j][0];
    float4 r0 = *reinterpret_cast<const float4*>(xr + kb);
    float4 r1 = *reinterpret_cast<const float4*>(xr + kb + 4);
    float4 r2 = *reinterpret_cast<const float4*>(xr + 16 + kb);
    float4 r3 = *reinterpret_cast<const float4*>(xr + 16 + kb + 4);
    float v0[8] = {r0.x, r0.y, r0.z, r0.w, r1.x, r1.y, r1.z, r1.w};
    float v1[8] = {r2.x, r2.y, r2.z, r2.w, r3.x, r3.y, r3.z, r3.w};

    half8 fLo, fHi;
    float s0a = 0.f, s1a = 0.f;
#pragma unroll
    for (int e = 0; e < 8; ++e) {
        float a = v0[e] * sl[e];
        s0a = fmaf(a, a, s0a);
        fLo[e] = (_Float16)a;
        float b = v1[e] * sh[e];
        s1a = fmaf(b, b, s1a);
        fHi[e] = (_Float16)b;
    }
    float sqp    = s0a + s1a;
    float sqfull = sqp + __shfl_xor(sqp, 32);   // |x_row_j|^2
    if (hl == 0) SQ[w][j] = sqfull;             // same-wave LDS: in-order, no barrier

    // ---- Gram: G = Xl * Xl^T (A-frag == B-frag) ----
    f32x16 C = {};
    C = __builtin_amdgcn_mfma_f32_32x32x16_f16(fLo, fLo, C, 0, 0, 0);
    C = __builtin_amdgcn_mfma_f32_32x32x16_f16(fHi, fHi, C, 0, 0, 0);

    // ---- per-location coefficient ----
    const float scl = scales[loc];
    const float nm  = nug[loc];
    const float sig  = __expf(sigp[0] + sigp[1] * __logf(scl));
    const float coef = frac[0] * sig * sig / nm;
    const bool  bz   = (bidx[loc] == 0);

    // ---- matern epilogue on C (col=j, row=(r&3)+8*(r>>2)+4*hl); store g ----
    float* gout = out + (size_t)loc * 1024;
    const float* sqb = &SQ[w][4 * hl];
#pragma unroll
    for (int r = 0; r < 16; ++r) {
        const int row0 = (r & 3) + 8 * (r >> 2);
        const int i    = row0 + 4 * hl;
        const bool dia = (j == i);
        float sqi = sqb[row0];                         // ds_read b32 (broadcast per half)
        float d2  = fmaf(-2.0f, C[r], sqi + sqfull);
        d2 = dia ? 0.0f : fmaxf(d2, 0.0f);
        float s3d = __fsqrt_rn(3.0f * d2);
        float nl  = (1.0f + s3d) * __expf(-s3d);
        float dg  = dia ? 1.0f : 0.0f;
        float gv  = fmaf(coef, nl, dg);
        if (bz) gv = dg;
        gout[i * 32 + j] = gv;                         // 2x128B lines per instr
    }

    // ---- nug_mean passthrough ----
    if (tid < 4) {
        int lc = loc0 + tid; if (lc >= n_loc) lc = n_loc - 1;
        out[(size_t)n_loc * 2048 + lc] = nug[lc];
    }
}

// ================= K2: Cholesky of g (no MFMA -> clean VGPR allocation) =================
__global__ __launch_bounds__(256, 6) void chol_kernel(
    const float* __restrict__ g,       // (n_loc, 32, 32) — K1's output
    float* __restrict__ lout,          // (n_loc, 32, 32)
    int n_loc)
{
    const int tid  = threadIdx.x;
    const int w    = tid >> 6;
    const int lane = tid & 63;
    const int j    = lane & 31;

    int loc = blockIdx.x * 4 + w; if (loc >= n_loc) loc = n_loc - 1;

    // lane j loads row j of G (L3-resident from K1); halves duplicate, harmless
    const float* grow = g + (size_t)loc * 1024 + (size_t)j * 32;
    float av[32];
#pragma unroll
    for (int c = 0; c < 8; ++c) {
        float4 v = *reinterpret_cast<const float4*>(grow + 4 * c);
        av[4 * c + 0] = v.x; av[4 * c + 1] = v.y;
        av[4 * c + 2] = v.z; av[4 * c + 3] = v.w;
    }

    Chol<0>::run(av);

    if (lane < 32) {
        float* lrow = lout + (size_t)loc * 1024 + (size_t)j * 32;
#pragma unroll
        for (int c = 0; c < 8; ++c) {
            float4 wv;
            wv.x = (4 * c + 0 <= j) ? av[4 * c + 0] : 0.f;
            wv.y = (4 * c + 1 <= j) ? av[4 * c + 1] : 0.f;
            wv.z = (4 * c + 2 <= j) ? av[4 * c + 2] : 0.f;
            wv.w = (4 * c + 3 <= j) ? av[4 * c + 3] : 0.f;
            *reinterpret_cast<float4*>(&lrow[4 * c]) = wv;
        }
    }
}

extern "C" void kernel_launch(void* const* d_in, const int* in_sizes, int n_in,
                              void* d_out, int out_size, void* d_ws, size_t ws_size,
                              hipStream_t stream) {
    const float* aug    = (const float*)d_in[0];
    const float* scales = (const float*)d_in[1];
    const float* nug    = (const float*)d_in[2];
    const float* frac   = (const float*)d_in[3];
    const int*   bidx   = (const int*)  d_in[4];
    const float* thq    = (const float*)d_in[5];
    const float* sigp   = (const float*)d_in[6];
    const float* lens   = (const float*)d_in[7];
    const int n_loc = in_sizes[1];

    float* out = (float*)d_out;
    const int nblk = (n_loc + 3) / 4;

    g_kernel<<<nblk, 256, 0, stream>>>(aug, scales, nug, frac, bidx, thq,
                                       sigp, lens, out, n_loc);
    chol_kernel<<<nblk, 256, 0, stream>>>(out, out + (size_t)n_loc * 1024, n_loc);
}